// Round 6
// baseline (1080.028 us; speedup 1.0000x reference)
//
#include <hip/hip_runtime.h>

// ---------------------------------------------------------------------------
// D=256 HEADS=8 DH=32 LEVELS=4 POINTS=4 DFFN=1024 B=8 NQ=300 NC=16
// M1 = 38400, LEN_IN = 5440, value rows = 43520
// SPATIAL = (64,64),(32,32),(16,16),(8,8); level starts 0,4096,5120,5376
// ---------------------------------------------------------------------------

typedef __bf16 bf16x8 __attribute__((ext_vector_type(8)));
typedef float  f32x4  __attribute__((ext_vector_type(4)));
typedef float  f32x2  __attribute__((ext_vector_type(2)));

__device__ __forceinline__ unsigned pk_bf16(float lo, float hi)
{
    unsigned a = __float_as_uint(lo) + 0x8000u;
    unsigned b = __float_as_uint(hi) + 0x8000u;
    return __builtin_amdgcn_perm(b, a, 0x07060302u);
}
__device__ __forceinline__ unsigned short f2bf(float v)
{
    return (unsigned short)((__float_as_uint(v) + 0x8000u) >> 16);
}
__device__ __forceinline__ float bf_lo(unsigned u) { return __uint_as_float(u << 16); }
__device__ __forceinline__ float bf_hi(unsigned u) { return __uint_as_float(u & 0xffff0000u); }
__device__ __forceinline__ float bf1(unsigned short u) { return __uint_as_float((unsigned)u << 16); }
__device__ __forceinline__ f32x2 bfpair(unsigned u)
{
    f32x2 r;
    r.x = __uint_as_float(u << 16);
    r.y = __uint_as_float(u & 0xffff0000u);
    return r;
}

// ---------------------------------------------------------------------------
// Weight pre-conversion fp32 -> bf16 (8 segments, one dispatch).
// ---------------------------------------------------------------------------
struct WcvtArgs {
    const float* src[8];
    unsigned short* dst[8];
    int n4[8];
};

__global__ __launch_bounds__(256) void wcvt(WcvtArgs a)
{
    const int gid = blockIdx.x * 256 + threadIdx.x;
    const int stride = gridDim.x * 256;
#pragma unroll
    for (int s = 0; s < 8; s++) {
        const float4* sp = (const float4*)a.src[s];
        uint2* dp = (uint2*)a.dst[s];
        for (int i = gid; i < a.n4[s]; i += stride) {
            float4 f = sp[i];
            uint2 o; o.x = pk_bf16(f.x, f.y); o.y = pk_bf16(f.z, f.w);
            dp[i] = o;
        }
    }
}

// ---------------------------------------------------------------------------
// A-stationary GEMM core: block = 64 A-rows staged ONCE in LDS (bf16, rows
// padded to 264 shorts -> 2-way bank aliasing only), then loop over ALL
// output columns reading W fragments (16B/lane dwordx4) straight from
// global (weights are L1/L2-resident). 4 waves, wave = 16 rows. Inner loop
// is 1:1 MFMA : B-load. KC = K/256 chunks; KC>1 requires groups==1
// (accumulators persist across chunks). NF = 16-col frags per group.
// ---------------------------------------------------------------------------
template <int ABF16, int NF, int KC>
__device__ __forceinline__ void gemm_astat(
    const void* __restrict__ Xv, const float* __restrict__ Y,
    const unsigned short* __restrict__ Wb, const float* __restrict__ bias,
    void* __restrict__ Cv, int outbf16, int relu,
    int row0, int N, int groups, unsigned short (*sA)[264])
{
    const int tid  = threadIdx.x;
    const int lane = tid & 63;
    const int wv   = tid >> 6;
    const int lm   = lane & 15;
    const int ko   = (lane >> 4) << 3;   // k element offset (0,8,16,24)
    const int q4   = (lane >> 4) << 2;   // C/D row base within 16
    const int K    = KC * 256;

    const int arow = tid >> 2;           // staging row 0..63
    const int aseg = tid & 3;            // 64-elem segment

    auto stage = [&](int kc) {
        uint4* dst = (uint4*)&sA[arow][aseg * 64];
        if (ABF16) {
            const uint4* Ar = (const uint4*)((const unsigned short*)Xv +
                              (size_t)(row0 + arow) * K + kc * 256 + aseg * 64);
#pragma unroll
            for (int i = 0; i < 8; i++) {
                const int j = (i + aseg) & 7;   // bank-spread rotation
                dst[j] = Ar[j];
            }
        } else {
            const float* Ar = (const float*)Xv + (size_t)(row0 + arow) * 256 + aseg * 64;
            const float* Yr = Y ? (Y + (size_t)(row0 + arow) * 256 + aseg * 64) : nullptr;
#pragma unroll
            for (int i = 0; i < 8; i++) {
                const int j = (i + aseg) & 7;
                float4 f0 = ((const float4*)Ar)[2 * j];
                float4 f1 = ((const float4*)Ar)[2 * j + 1];
                if (Y) {
                    float4 g0 = ((const float4*)Yr)[2 * j];
                    float4 g1 = ((const float4*)Yr)[2 * j + 1];
                    f0.x += g0.x; f0.y += g0.y; f0.z += g0.z; f0.w += g0.w;
                    f1.x += g1.x; f1.y += g1.y; f1.z += g1.z; f1.w += g1.w;
                }
                uint4 u;
                u.x = pk_bf16(f0.x, f0.y); u.y = pk_bf16(f0.z, f0.w);
                u.z = pk_bf16(f1.x, f1.y); u.w = pk_bf16(f1.z, f1.w);
                dst[j] = u;
            }
        }
    };

    const int rowb = row0 + wv * 16 + q4;

    auto epi = [&](f32x4* acc, int colg) {
#pragma unroll
        for (int nf = 0; nf < NF; nf++) {
            const int col = colg + nf * 16 + lm;
            const float bsv = bias[col];
#pragma unroll
            for (int rr = 0; rr < 4; rr++) {
                float v = acc[nf][rr] + bsv;
                if (relu) v = fmaxf(v, 0.f);
                if (outbf16)
                    ((unsigned short*)Cv)[(size_t)(rowb + rr) * N + col] = f2bf(v);
                else
                    ((float*)Cv)[(size_t)(rowb + rr) * N + col] = v;
            }
        }
    };

    if (KC == 1) {
        stage(0);
        __syncthreads();
        bf16x8 av[8];
#pragma unroll
        for (int ks = 0; ks < 8; ks++)
            av[ks] = *(const bf16x8*)&sA[wv * 16 + lm][ks * 32 + ko];

        for (int g = 0; g < groups; g++) {
            const int colg = g * (NF * 16);
            f32x4 acc[NF] = {};
#pragma unroll
            for (int nf = 0; nf < NF; nf++) {
                const unsigned short* Wr = Wb + (size_t)(colg + nf * 16 + lm) * K + ko;
                bf16x8 bv[8];
#pragma unroll
                for (int ks = 0; ks < 8; ks++)
                    bv[ks] = *(const bf16x8*)(Wr + ks * 32);
#pragma unroll
                for (int ks = 0; ks < 8; ks++)
                    acc[nf] = __builtin_amdgcn_mfma_f32_16x16x32_bf16(
                        av[ks], bv[ks], acc[nf], 0, 0, 0);
            }
            epi(acc, colg);
        }
    } else {
        f32x4 acc[NF] = {};
        for (int kc = 0; kc < KC; kc++) {
            if (kc) __syncthreads();
            stage(kc);
            __syncthreads();
            bf16x8 av[8];
#pragma unroll
            for (int ks = 0; ks < 8; ks++)
                av[ks] = *(const bf16x8*)&sA[wv * 16 + lm][ks * 32 + ko];
#pragma unroll
            for (int nf = 0; nf < NF; nf++) {
                const unsigned short* Wr = Wb + (size_t)(nf * 16 + lm) * K + kc * 256 + ko;
                bf16x8 bv[8];
#pragma unroll
                for (int ks = 0; ks < 8; ks++)
                    bv[ks] = *(const bf16x8*)(Wr + ks * 32);
#pragma unroll
                for (int ks = 0; ks < 8; ks++)
                    acc[nf] = __builtin_amdgcn_mfma_f32_16x16x32_bf16(
                        av[ks], bv[ks], acc[nf], 0, 0, 0);
            }
        }
        epi(acc, 0);
    }
}

template <int ABF16, int NF, int KC>
__global__ __launch_bounds__(256) void gemm_one(
    const void* __restrict__ Xv, const float* __restrict__ Y,
    const unsigned short* __restrict__ Wb, const float* __restrict__ bias,
    void* __restrict__ Cv, int outbf16, int relu, int N, int groups)
{
    __shared__ unsigned short sA[64][264];
    gemm_astat<ABF16, NF, KC>(Xv, Y, Wb, bias, Cv, outbf16, relu,
                              blockIdx.x * 64, N, groups, sA);
}

// fused: qk (b<600, N=512, A=tgt+qpos), v (b<1200, N=256, A=tgt),
// value (b<1880, N=256, A=src over 43520 rows)
__global__ __launch_bounds__(256) void gemm_qkvval(
    const float* __restrict__ tgt, const float* __restrict__ qpos,
    const unsigned short* __restrict__ Wsa, const float* __restrict__ bsa,
    unsigned short* __restrict__ qkB, unsigned short* __restrict__ vB,
    const float* __restrict__ src,
    const unsigned short* __restrict__ Wval, const float* __restrict__ bval,
    unsigned short* __restrict__ valB)
{
    __shared__ unsigned short sA[64][264];
    const int b = blockIdx.x;
    if (b < 600)
        gemm_astat<0, 8, 1>(tgt, qpos, Wsa, bsa, qkB, 1, 0, b * 64, 512, 4, sA);
    else if (b < 1200)
        gemm_astat<0, 8, 1>(tgt, nullptr, Wsa + 512 * 256, bsa + 512, vB, 1, 0,
                            (b - 600) * 64, 256, 2, sA);
    else
        gemm_astat<0, 8, 1>(src, nullptr, Wval, bval, valB, 1, 0,
                            (b - 1200) * 64, 256, 2, sA);
}

// fused: off (b<600, N=256, bf16 out) and attw logits (b<1200, N=128, fp32)
__global__ __launch_bounds__(256) void gemm_offaw(
    const unsigned short* __restrict__ X,
    const unsigned short* __restrict__ Woff, const float* __restrict__ boff,
    unsigned short* __restrict__ offB,
    const unsigned short* __restrict__ Watt, const float* __restrict__ batt,
    float* __restrict__ awL)
{
    __shared__ unsigned short sA[64][264];
    const int b = blockIdx.x;
    if (b < 600)
        gemm_astat<1, 8, 1>(X, nullptr, Woff, boff, offB, 1, 0, b * 64, 256, 2, sA);
    else
        gemm_astat<1, 8, 1>(X, nullptr, Watt, batt, awL, 0, 0, (b - 600) * 64, 128, 1, sA);
}

// ---------------------------------------------------------------------------
// Self-attention over NC=16 groups; bf16 LDS, padded rows (conflict-free).
// ---------------------------------------------------------------------------
__global__ __launch_bounds__(256) void attn16(
    const unsigned short* __restrict__ QK, const unsigned short* __restrict__ V,
    unsigned short* __restrict__ O)
{
    __shared__ unsigned short sqk[16][520];
    __shared__ unsigned short sv[16][264];
    __shared__ float sp[128][17];

    const int g = blockIdx.x;
    const int tid = threadIdx.x;

    const uint4* qg = (const uint4*)(QK + (size_t)g * 8192);
    for (int i = tid; i < 1024; i += 256)
        *(uint4*)&sqk[i >> 6][(i & 63) * 8] = qg[i];
    const uint4* vg = (const uint4*)(V + (size_t)g * 4096);
    for (int i = tid; i < 512; i += 256)
        *(uint4*)&sv[i >> 5][(i & 31) * 8] = vg[i];
    __syncthreads();

#pragma unroll 2
    for (int s = tid; s < 2048; s += 256) {
        const int h = s >> 8, qi = (s >> 4) & 15, kj = s & 15;
        const uint4* qp = (const uint4*)&sqk[qi][h * 32];
        const uint4* kp = (const uint4*)&sqk[kj][256 + h * 32];
        float acc = 0.f;
#pragma unroll
        for (int c = 0; c < 4; c++) {
            uint4 qu = qp[c];
            uint4 ku = kp[c];
            acc += bf_lo(qu.x) * bf_lo(ku.x) + bf_hi(qu.x) * bf_hi(ku.x)
                 + bf_lo(qu.y) * bf_lo(ku.y) + bf_hi(qu.y) * bf_hi(ku.y)
                 + bf_lo(qu.z) * bf_lo(ku.z) + bf_hi(qu.z) * bf_hi(ku.z)
                 + bf_lo(qu.w) * bf_lo(ku.w) + bf_hi(qu.w) * bf_hi(ku.w);
        }
        sp[s >> 4][s & 15] = acc * 0.17677669529663687f;
    }
    __syncthreads();

    if (tid < 128) {
        float* row = sp[tid];
        float mx = row[0];
#pragma unroll
        for (int j = 1; j < 16; j++) mx = fmaxf(mx, row[j]);
        float sum = 0.f;
#pragma unroll
        for (int j = 0; j < 16; j++) { float e = __expf(row[j] - mx); row[j] = e; sum += e; }
        float inv = 1.f / sum;
#pragma unroll
        for (int j = 0; j < 16; j++) row[j] *= inv;
    }
    __syncthreads();

    uint2* og = (uint2*)(O + (size_t)g * 4096);
    for (int o = tid; o < 1024; o += 256) {
        const int qi = o >> 6, cq = o & 63, h = cq >> 3;
        const float* pr = sp[h * 16 + qi];
        float a0 = 0.f, a1 = 0.f, a2 = 0.f, a3 = 0.f;
#pragma unroll
        for (int j = 0; j < 16; j++) {
            uint2 u = *(const uint2*)&sv[j][cq * 4];
            float p = pr[j];
            a0 += p * bf_lo(u.x); a1 += p * bf_hi(u.x);
            a2 += p * bf_lo(u.y); a3 += p * bf_hi(u.y);
        }
        uint2 r; r.x = pk_bf16(a0, a1); r.y = pk_bf16(a2, a3);
        og[o] = r;
    }
}

// ---------------------------------------------------------------------------
// Residual + LN, wave-per-row (4 rows/block), butterfly shuffles, no LDS.
// ---------------------------------------------------------------------------
template <int XBF16, int WRITE2, int ADDQ>
__global__ __launch_bounds__(256) void ln_res4(
    const void* __restrict__ Xv, const float* __restrict__ R,
    const float* __restrict__ w, const float* __restrict__ b,
    float* __restrict__ out, unsigned short* __restrict__ out2,
    const float* __restrict__ qpos)
{
    const int row = blockIdx.x * 4 + (threadIdx.x >> 6);
    const int lane = threadIdx.x & 63;
    const size_t base = (size_t)row * 256 + lane * 4;

    float x0, x1, x2, x3;
    if (XBF16) {
        uint2 u = *(const uint2*)((const unsigned short*)Xv + base);
        x0 = bf_lo(u.x); x1 = bf_hi(u.x); x2 = bf_lo(u.y); x3 = bf_hi(u.y);
    } else {
        float4 f = *(const float4*)((const float*)Xv + base);
        x0 = f.x; x1 = f.y; x2 = f.z; x3 = f.w;
    }
    float4 r4 = *(const float4*)&R[base];
    float v0 = x0 + r4.x, v1 = x1 + r4.y, v2 = x2 + r4.z, v3 = x3 + r4.w;

    float s = v0 + v1 + v2 + v3;
#pragma unroll
    for (int o = 32; o > 0; o >>= 1) s += __shfl_xor(s, o);
    const float mean = s * (1.f / 256.f);
    const float d0 = v0 - mean, d1 = v1 - mean, d2 = v2 - mean, d3 = v3 - mean;
    float q = d0 * d0 + d1 * d1 + d2 * d2 + d3 * d3;
#pragma unroll
    for (int o = 32; o > 0; o >>= 1) q += __shfl_xor(q, o);
    const float rs = rsqrtf(q * (1.f / 256.f) + 1e-5f);

    float4 w4 = *(const float4*)&w[lane * 4];
    float4 b4 = *(const float4*)&b[lane * 4];
    float y0 = d0 * rs * w4.x + b4.x;
    float y1 = d1 * rs * w4.y + b4.y;
    float y2 = d2 * rs * w4.z + b4.z;
    float y3 = d3 * rs * w4.w + b4.w;

    float4 o4; o4.x = y0; o4.y = y1; o4.z = y2; o4.w = y3;
    *(float4*)&out[base] = o4;
    if (WRITE2) {
        float z0 = y0, z1 = y1, z2 = y2, z3 = y3;
        if (ADDQ) {
            float4 qp4 = *(const float4*)&qpos[base];
            z0 += qp4.x; z1 += qp4.y; z2 += qp4.z; z3 += qp4.w;
        }
        uint2 u; u.x = pk_bf16(z0, z1); u.y = pk_bf16(z2, z3);
        *(uint2*)(out2 + base) = u;
    }
}

// ---------------------------------------------------------------------------
// MS-deformable sampling, 4 queries/block (1 wave each), bf16 value.
// ---------------------------------------------------------------------------
__global__ __launch_bounds__(256) void ms_sample4(
    const unsigned short* __restrict__ VAL, const unsigned short* __restrict__ OFF,
    const float* __restrict__ AWL, const float* __restrict__ REF,
    unsigned short* __restrict__ OUT)
{
    __shared__ unsigned short soff[1024];   // [4][256]
    __shared__ float saw[512];              // [4][128] logits -> probs
    __shared__ float sref[32];              // [4][8]
    __shared__ float swt[4][16][8][4];
    __shared__ int   sidx[4][16][8][4];

    const int m0 = blockIdx.x * 4, tid = threadIdx.x;

    ((uint2*)soff)[tid] = ((const uint2*)(OFF + (size_t)m0 * 256))[tid];
    ((float2*)saw)[tid] = ((const float2*)(AWL + (size_t)m0 * 128))[tid];
    if (tid < 32) sref[tid] = REF[(size_t)m0 * 8 + tid];
    __syncthreads();

    if (tid < 32) {
        float* row = &saw[tid * 16];
        float mx = row[0];
#pragma unroll
        for (int j = 1; j < 16; j++) mx = fmaxf(mx, row[j]);
        float s = 0.f, e[16];
#pragma unroll
        for (int j = 0; j < 16; j++) { e[j] = __expf(row[j] - mx); s += e[j]; }
        float inv = 1.f / s;
#pragma unroll
        for (int j = 0; j < 16; j++) row[j] = e[j] * inv;
    }
    __syncthreads();

    for (int c = tid; c < 512; c += 256) {
        const int qi = c >> 7, h = c & 7, j = (c >> 3) & 15;
        const int l = j >> 2, p = j & 3;
        const int Wl = 64 >> l;
        const int st = (l == 0) ? 0 : (l == 1) ? 4096 : (l == 2) ? 5120 : 5376;
        const float fS = (float)Wl;
        const unsigned short* ob = &soff[qi * 256 + h * 32 + l * 8 + p * 2];
        const float x = sref[qi * 8 + l * 2 + 0] * fS + bf1(ob[0]) - 0.5f;
        const float y = sref[qi * 8 + l * 2 + 1] * fS + bf1(ob[1]) - 0.5f;
        const float x0f = floorf(x), y0f = floorf(y);
        const float fx = x - x0f, fy = y - y0f;
        const int x0 = (int)x0f, y0 = (int)y0f;
        const int x1 = x0 + 1, y1 = y0 + 1;
        const float vx0 = (x0 >= 0 && x0 < Wl) ? 1.f : 0.f;
        const float vx1 = (x1 >= 0 && x1 < Wl) ? 1.f : 0.f;
        const float vy0 = (y0 >= 0 && y0 < Wl) ? 1.f : 0.f;
        const float vy1 = (y1 >= 0 && y1 < Wl) ? 1.f : 0.f;
        const int cx0 = min(max(x0, 0), Wl - 1);
        const int cx1 = min(max(x1, 0), Wl - 1);
        const int cy0 = min(max(y0, 0), Wl - 1);
        const int cy1 = min(max(y1, 0), Wl - 1);
        const float aw = saw[qi * 128 + h * 16 + j];
        float4 w4;
        w4.x = (1.f - fx) * (1.f - fy) * vx0 * vy0 * aw;
        w4.y = fx * (1.f - fy) * vx1 * vy0 * aw;
        w4.z = (1.f - fx) * fy * vx0 * vy1 * aw;
        w4.w = fx * fy * vx1 * vy1 * aw;
        int4 i4;
        i4.x = (st + cy0 * Wl + cx0) << 9;
        i4.y = (st + cy0 * Wl + cx1) << 9;
        i4.z = (st + cy1 * Wl + cx0) << 9;
        i4.w = (st + cy1 * Wl + cx1) << 9;
        *(float4*)&swt[qi][j][h][0] = w4;
        *(int4*)&sidx[qi][j][h][0]  = i4;
    }
    __syncthreads();

    const int qi = tid >> 6, lane = tid & 63, h = lane >> 3;
    const int m = m0 + qi, bb = m / 4800;
    const char* vb = (const char*)VAL + (size_t)bb * 5440 * 512 + lane * 8;

    f32x2 a01 = {0.f, 0.f}, a23 = {0.f, 0.f};
#pragma unroll 4
    for (int j = 0; j < 16; j++) {
        const float4 w = *(const float4*)&swt[qi][j][h][0];
        const int4  id = *(const int4*)&sidx[qi][j][h][0];
        uint2 c0 = *(const uint2*)(vb + id.x);
        uint2 c1 = *(const uint2*)(vb + id.y);
        uint2 c2 = *(const uint2*)(vb + id.z);
        uint2 c3 = *(const uint2*)(vb + id.w);
        a01 += w.x * bfpair(c0.x) + w.y * bfpair(c1.x)
             + w.z * bfpair(c2.x) + w.w * bfpair(c3.x);
        a23 += w.x * bfpair(c0.y) + w.y * bfpair(c1.y)
             + w.z * bfpair(c2.y) + w.w * bfpair(c3.y);
    }
    uint2 o;
    o.x = pk_bf16(a01.x, a01.y);
    o.y = pk_bf16(a23.x, a23.y);
    *(uint2*)(OUT + (size_t)m * 256 + lane * 4) = o;
}

// ---------------------------------------------------------------------------
// Launch
// ---------------------------------------------------------------------------
extern "C" void kernel_launch(void* const* d_in, const int* in_sizes, int n_in,
                              void* d_out, int out_size, void* d_ws, size_t ws_size,
                              hipStream_t stream)
{
    const float* tgt        = (const float*)d_in[0];
    const float* qpos       = (const float*)d_in[1];
    const float* refp       = (const float*)d_in[2];
    const float* src        = (const float*)d_in[3];
    const float* sa_in_w    = (const float*)d_in[7];
    const float* sa_in_b    = (const float*)d_in[8];
    const float* sa_out_w   = (const float*)d_in[9];
    const float* sa_out_b   = (const float*)d_in[10];
    const float* norm2_w    = (const float*)d_in[11];
    const float* norm2_b    = (const float*)d_in[12];
    const float* ca_value_w = (const float*)d_in[13];
    const float* ca_value_b = (const float*)d_in[14];
    const float* ca_off_w   = (const float*)d_in[15];
    const float* ca_off_b   = (const float*)d_in[16];
    const float* ca_attw_w  = (const float*)d_in[17];
    const float* ca_attw_b  = (const float*)d_in[18];
    const float* ca_out_w   = (const float*)d_in[19];
    const float* ca_out_b   = (const float*)d_in[20];
    const float* norm1_w    = (const float*)d_in[21];
    const float* norm1_b    = (const float*)d_in[22];
    const float* lin1_w     = (const float*)d_in[23];
    const float* lin1_b     = (const float*)d_in[24];
    const float* lin2_w     = (const float*)d_in[25];
    const float* lin2_b     = (const float*)d_in[26];
    const float* norm3_w    = (const float*)d_in[27];
    const float* norm3_b    = (const float*)d_in[28];
    float* out = (float*)d_out;

    float* ws = (float*)d_ws;
    float* A  = ws;
    float* Bx = A  + 9830400;
    float* Cx = Bx + 4915200;
    float* Dx = Cx + 4915200;
    float* Ex = Dx + 4915200;
    float* Fx = Ex + 5570560;
    float* Gx = Fx + 19660800;

    unsigned short* qkB   = (unsigned short*)A;
    float*          t1    = A;
    float*          t2    = A;
    unsigned short* vB    = (unsigned short*)Bx;
    unsigned short* t1qB  = (unsigned short*)Bx;
    unsigned short* sampB = (unsigned short*)Bx;
    unsigned short* l2B   = (unsigned short*)Bx;
    unsigned short* aoB   = (unsigned short*)Cx;
    unsigned short* offB  = (unsigned short*)Cx;
    unsigned short* coB   = (unsigned short*)Cx;
    unsigned short* t2B   = (unsigned short*)Cx;
    unsigned short* soB   = (unsigned short*)Dx;
    float*          awL   = Dx;
    unsigned short* valB  = (unsigned short*)Ex;
    unsigned short* hidB  = (unsigned short*)Fx;
    unsigned short* wG    = (unsigned short*)Gx;

    unsigned short* wSAIN  = wG;            // 768*256
    unsigned short* wSAOUT = wG + 196608;   // 256*256
    unsigned short* wVAL   = wG + 262144;   // 256*256
    unsigned short* wOFF   = wG + 327680;   // 256*256
    unsigned short* wATT   = wG + 393216;   // 128*256
    unsigned short* wCAOUT = wG + 425984;   // 256*256
    unsigned short* wL1    = wG + 491520;   // 1024*256
    unsigned short* wL2    = wG + 753664;   // 256*1024

    dim3 blk(256);

    WcvtArgs wa;
    wa.src[0] = sa_in_w;    wa.dst[0] = wSAIN;  wa.n4[0] = 196608 / 4;
    wa.src[1] = sa_out_w;   wa.dst[1] = wSAOUT; wa.n4[1] = 65536 / 4;
    wa.src[2] = ca_value_w; wa.dst[2] = wVAL;   wa.n4[2] = 65536 / 4;
    wa.src[3] = ca_off_w;   wa.dst[3] = wOFF;   wa.n4[3] = 65536 / 4;
    wa.src[4] = ca_attw_w;  wa.dst[4] = wATT;   wa.n4[4] = 32768 / 4;
    wa.src[5] = ca_out_w;   wa.dst[5] = wCAOUT; wa.n4[5] = 65536 / 4;
    wa.src[6] = lin1_w;     wa.dst[6] = wL1;    wa.n4[6] = 262144 / 4;
    wa.src[7] = lin2_w;     wa.dst[7] = wL2;    wa.n4[7] = 262144 / 4;
    wcvt<<<512, blk, 0, stream>>>(wa);

    // --- self-attention (+ value GEMM fused in) ---
    gemm_qkvval<<<1880, blk, 0, stream>>>(tgt, qpos, wSAIN, sa_in_b, qkB, vB,
                                          src, wVAL, ca_value_b, valB);
    attn16<<<2400, blk, 0, stream>>>(qkB, vB, aoB);
    gemm_one<1, 8, 1><<<600, blk, 0, stream>>>(aoB, nullptr, wSAOUT, sa_out_b, soB, 1, 0, 256, 2);
    ln_res4<1, 1, 1><<<9600, blk, 0, stream>>>(soB, tgt, norm2_w, norm2_b, t1, t1qB, qpos);

    // --- MS deformable cross-attention ---
    gemm_offaw<<<1200, blk, 0, stream>>>(t1qB, wOFF, ca_off_b, offB, wATT, ca_attw_b, awL);
    ms_sample4<<<9600, blk, 0, stream>>>(valB, offB, awL, refp, sampB);
    gemm_one<1, 8, 1><<<600, blk, 0, stream>>>(sampB, nullptr, wCAOUT, ca_out_b, coB, 1, 0, 256, 2);
    ln_res4<1, 1, 0><<<9600, blk, 0, stream>>>(coB, t1, norm1_w, norm1_b, t2, t2B, nullptr);

    // --- FFN ---
    gemm_one<1, 8, 1><<<600, blk, 0, stream>>>(t2B, nullptr, wL1, lin1_b, hidB, 1, 1, 1024, 8);
    gemm_one<1, 16, 4><<<600, blk, 0, stream>>>(hidB, nullptr, wL2, lin2_b, l2B, 1, 0, 256, 1);
    ln_res4<1, 0, 0><<<9600, blk, 0, stream>>>(l2B, t2, norm3_w, norm3_b, out, nullptr, nullptr);
}